// Round 1
// baseline (1136.320 us; speedup 1.0000x reference)
//
#include <hip/hip_runtime.h>

#define D 512
#define T 50000
#define K 16

#define LAMBDA1 0.3366f
#define LR      0.1f
#define SHRINK_C (LR * LAMBDA1)
#define BETA1   0.9f
#define BETA2   0.999f
#define ADAM_EPS 1e-8f

__device__ __forceinline__ float sgn(float x) {
    return (x > 0.f) ? 1.f : ((x < 0.f) ? -1.f : 0.f);
}

// Initialize P, m, v, B (=P for iter 1) and the argmax slot. d_ws is poisoned
// 0xAA before every call, so everything must be re-initialized here.
__global__ void init_kernel(const float* __restrict__ Pin, float* __restrict__ P,
                            float* __restrict__ m, float* __restrict__ v,
                            float* __restrict__ B, unsigned long long* slot) {
    int idx = blockIdx.x * blockDim.x + threadIdx.x;
    if (idx < D * K) {
        float p = Pin[idx];
        P[idx] = p;
        m[idx] = 0.f;
        v[idx] = 0.f;
        B[idx] = p;   // iteration 1 uses the raw parameter
    }
    if (idx == 0) *slot = 0ull;
}

// One thread per column j: colsum_j = sum_i |E[i,j] - sum_k B[i,k]*A[k,j]|.
// Block-level argmax, then one atomicMax per block on a packed (sum_bits<<32 | j) key.
__global__ __launch_bounds__(256) void colsum_kernel(
        const float* __restrict__ E, const float* __restrict__ A,
        const float* __restrict__ B, unsigned long long* slot) {
    int j = blockIdx.x * blockDim.x + threadIdx.x;
    float acc = 0.f;
    if (j < T) {
        float a[K];
#pragma unroll
        for (int k = 0; k < K; ++k) a[k] = A[k * T + j];
#pragma unroll 4
        for (int i = 0; i < D; ++i) {
            float r = E[i * T + j];
            const float* Br = B + i * K;   // wave-uniform address -> s_load
#pragma unroll
            for (int k = 0; k < K; ++k) r -= Br[k] * a[k];
            acc += fabsf(r);
        }
    }
    // acc >= 0, so its float bit pattern is order-preserving as unsigned.
    unsigned long long key =
        (((unsigned long long)__float_as_uint(acc)) << 32) | (unsigned int)j;
    if (j >= T) key = 0ull;

#pragma unroll
    for (int off = 32; off > 0; off >>= 1) {
        unsigned long long o = __shfl_down(key, off, 64);
        if (o > key) key = o;
    }
    __shared__ unsigned long long wmax[8];
    int lane = threadIdx.x & 63, wid = threadIdx.x >> 6;
    if (lane == 0) wmax[wid] = key;
    __syncthreads();
    if (threadIdx.x == 0) {
        unsigned long long best = wmax[0];
        int nw = (int)(blockDim.x + 63) >> 6;
        for (int w = 1; w < nw; ++w)
            if (wmax[w] > best) best = wmax[w];
        atomicMax(slot, best);
    }
}

// Single block, 512 threads, thread i handles row i of P/B.
// Computes residual signs at column j*, B column-L1 argmax k*, gradient,
// optional shrink-chain factor, Adam step, and writes B = shrink(P) in place
// for the next iteration. Resets the argmax slot.
__global__ __launch_bounds__(512) void update_kernel(
        const float* __restrict__ E, const float* __restrict__ A,
        float* __restrict__ B, float* __restrict__ P,
        float* __restrict__ m, float* __restrict__ v,
        unsigned long long* slot, float bias1, float bias2, int shrinkGrad) {
    int i = threadIdx.x;   // 0..511
    __shared__ float colB[K];
    __shared__ int js_s, ks_s;
    if (i < K) colB[i] = 0.f;
    if (i == 0) js_s = (int)((*slot) & 0xffffffffull);
    __syncthreads();
    int js = js_s;

    float b[K];
#pragma unroll
    for (int k = 0; k < K; ++k) b[k] = B[i * K + k];

    // residual sign for row i at column j*
    float r = E[i * T + js];
#pragma unroll
    for (int k = 0; k < K; ++k) r -= b[k] * A[k * T + js];
    float s = sgn(r);

    // B column abs-sums: wave reduce then one LDS atomic per wave per k
#pragma unroll
    for (int k = 0; k < K; ++k) {
        float x = fabsf(b[k]);
#pragma unroll
        for (int off = 32; off > 0; off >>= 1) x += __shfl_down(x, off, 64);
        if ((threadIdx.x & 63) == 0) atomicAdd(&colB[k], x);
    }
    __syncthreads();
    if (i == 0) {
        int kb = 0;
        float best = colB[0];
        for (int k = 1; k < K; ++k)
            if (colB[k] > best) { best = colB[k]; kb = k; }   // first-max tie-break
        ks_s = kb;
        *slot = 0ull;   // reset for next iteration
    }
    __syncthreads();
    int ks = ks_s;

#pragma unroll
    for (int k = 0; k < K; ++k) {
        float g = -s * A[k * T + js];
        if (k == ks) g += LAMBDA1 * sgn(b[k]);
        float p = P[i * K + k];
        if (shrinkGrad) g *= sgn(p) * sgn(p - SHRINK_C);   // d shrink/dp a.e.
        float mm = BETA1 * m[i * K + k] + (1.f - BETA1) * g;
        float vv = BETA2 * v[i * K + k] + (1.f - BETA2) * g * g;
        m[i * K + k] = mm;
        v[i * K + k] = vv;
        p -= LR * (mm / bias1) / (sqrtf(vv / bias2) + ADAM_EPS);
        P[i * K + k] = p;
        B[i * K + k] = sgn(p) * fmaxf(0.f, fabsf(p - SHRINK_C));   // next B = shrink(P)
    }
}

// out = [shrink(P_final) (8192), A (800000)]. B already holds shrink(P_final).
__global__ void output_kernel(const float* __restrict__ B, const float* __restrict__ A,
                              float* __restrict__ out) {
    int idx = blockIdx.x * blockDim.x + threadIdx.x;
    if (idx < D * K) {
        out[idx] = B[idx];
    } else if (idx < D * K + K * T) {
        out[idx] = A[idx - D * K];
    }
}

extern "C" void kernel_launch(void* const* d_in, const int* in_sizes, int n_in,
                              void* d_out, int out_size, void* d_ws, size_t ws_size,
                              hipStream_t stream) {
    const float* E   = (const float*)d_in[0];   // (D, T)
    const float* Bin = (const float*)d_in[1];   // (D, K)
    const float* A   = (const float*)d_in[2];   // (K, T)
    float* out = (float*)d_out;

    float* P = (float*)d_ws;
    float* m = P + D * K;
    float* v = m + D * K;
    float* B = v + D * K;
    unsigned long long* slot = (unsigned long long*)((char*)d_ws + 4u * sizeof(float) * D * K);

    init_kernel<<<(D * K + 255) / 256, 256, 0, stream>>>(Bin, P, m, v, B, slot);

    for (int it = 1; it <= 10; ++it) {
        colsum_kernel<<<(T + 255) / 256, 256, 0, stream>>>(E, A, B, slot);
        float b1 = 1.f - powf(BETA1, (float)it);
        float b2 = 1.f - powf(BETA2, (float)it);
        update_kernel<<<1, 512, 0, stream>>>(E, A, B, P, m, v, slot, b1, b2,
                                             (it >= 2) ? 1 : 0);
    }

    output_kernel<<<(D * K + K * T + 255) / 256, 256, 0, stream>>>(B, A, out);
}

// Round 2
// 769.716 us; speedup vs baseline: 1.4763x; 1.4763x over previous
//
#include <hip/hip_runtime.h>

#define D 512
#define T 50000
#define K 16

#define ROWS_PER_SLICE 64
#define N_SLICES (D / ROWS_PER_SLICE)   // 8

#define LAMBDA1 0.3366f
#define LR      0.1f
#define SHRINK_C (LR * LAMBDA1)
#define BETA1   0.9f
#define BETA2   0.999f
#define ADAM_EPS 1e-8f

__device__ __forceinline__ float sgn(float x) {
    return (x > 0.f) ? 1.f : ((x < 0.f) ? -1.f : 0.f);
}

// Initialize P, m, v, B (=P for iter 1) and the argmax slot. d_ws is poisoned
// 0xAA before every call, so everything must be re-initialized here.
__global__ void init_kernel(const float* __restrict__ Pin, float* __restrict__ P,
                            float* __restrict__ m, float* __restrict__ v,
                            float* __restrict__ B, unsigned long long* slot) {
    int idx = blockIdx.x * blockDim.x + threadIdx.x;
    if (idx < D * K) {
        float p = Pin[idx];
        P[idx] = p;
        m[idx] = 0.f;
        v[idx] = 0.f;
        B[idx] = p;   // iteration 1 uses the raw parameter
    }
    if (idx == 0) *slot = 0ull;
}

// Partial column abs-sums: block (bx, s) covers 256 columns x 64 rows.
// Thread j accumulates sum_{i in slice} |E[i,j] - sum_k B[i,k]*A[k,j]|
// and writes partial[s*T + j]. Deterministic (no fp atomics).
__global__ __launch_bounds__(256) void partial_colsum_kernel(
        const float* __restrict__ E, const float* __restrict__ A,
        const float* __restrict__ B, float* __restrict__ partial) {
    int j = blockIdx.x * blockDim.x + threadIdx.x;
    int s = blockIdx.y;
    if (j >= T) return;

    float a[K];
#pragma unroll
    for (int k = 0; k < K; ++k) a[k] = A[k * T + j];

    int r0 = s * ROWS_PER_SLICE;
    float acc = 0.f;
#pragma unroll 4
    for (int ii = 0; ii < ROWS_PER_SLICE; ++ii) {
        int i = r0 + ii;
        float r = E[i * T + j];
        const float* Br = B + i * K;   // wave-uniform address -> s_load
#pragma unroll
        for (int k = 0; k < K; ++k) r -= Br[k] * a[k];
        acc += fabsf(r);
    }
    partial[s * T + j] = acc;
}

// Sum the N_SLICES partials per column and argmax via packed
// (sum_bits<<32 | j) atomicMax on a single slot.
__global__ __launch_bounds__(256) void reduce_argmax_kernel(
        const float* __restrict__ partial, unsigned long long* slot) {
    int j = blockIdx.x * blockDim.x + threadIdx.x;
    float acc = 0.f;
    if (j < T) {
#pragma unroll
        for (int s = 0; s < N_SLICES; ++s) acc += partial[s * T + j];
    }
    // acc >= 0, so its float bit pattern is order-preserving as unsigned.
    unsigned long long key =
        (((unsigned long long)__float_as_uint(acc)) << 32) | (unsigned int)j;
    if (j >= T) key = 0ull;

#pragma unroll
    for (int off = 32; off > 0; off >>= 1) {
        unsigned long long o = __shfl_down(key, off, 64);
        if (o > key) key = o;
    }
    __shared__ unsigned long long wmax[4];
    int lane = threadIdx.x & 63, wid = threadIdx.x >> 6;
    if (lane == 0) wmax[wid] = key;
    __syncthreads();
    if (threadIdx.x == 0) {
        unsigned long long best = wmax[0];
        for (int w = 1; w < 4; ++w)
            if (wmax[w] > best) best = wmax[w];
        atomicMax(slot, best);
    }
}

// Single block, 512 threads, thread i handles row i of P/B.
// Computes residual signs at column j*, B column-L1 argmax k*, gradient,
// optional shrink-chain factor, Adam step, and writes B = shrink(P) in place
// for the next iteration. Resets the argmax slot.
__global__ __launch_bounds__(512) void update_kernel(
        const float* __restrict__ E, const float* __restrict__ A,
        float* __restrict__ B, float* __restrict__ P,
        float* __restrict__ m, float* __restrict__ v,
        unsigned long long* slot, float bias1, float bias2, int shrinkGrad) {
    int i = threadIdx.x;   // 0..511
    __shared__ float colB[K];
    __shared__ int js_s, ks_s;
    if (i < K) colB[i] = 0.f;
    if (i == 0) js_s = (int)((*slot) & 0xffffffffull);
    __syncthreads();
    int js = js_s;

    float b[K];
#pragma unroll
    for (int k = 0; k < K; ++k) b[k] = B[i * K + k];

    // residual sign for row i at column j*
    float r = E[i * T + js];
#pragma unroll
    for (int k = 0; k < K; ++k) r -= b[k] * A[k * T + js];
    float s = sgn(r);

    // B column abs-sums: wave reduce then one LDS atomic per wave per k
#pragma unroll
    for (int k = 0; k < K; ++k) {
        float x = fabsf(b[k]);
#pragma unroll
        for (int off = 32; off > 0; off >>= 1) x += __shfl_down(x, off, 64);
        if ((threadIdx.x & 63) == 0) atomicAdd(&colB[k], x);
    }
    __syncthreads();
    if (i == 0) {
        int kb = 0;
        float best = colB[0];
        for (int k = 1; k < K; ++k)
            if (colB[k] > best) { best = colB[k]; kb = k; }   // first-max tie-break
        ks_s = kb;
        *slot = 0ull;   // reset for next iteration
    }
    __syncthreads();
    int ks = ks_s;

#pragma unroll
    for (int k = 0; k < K; ++k) {
        float g = -s * A[k * T + js];
        if (k == ks) g += LAMBDA1 * sgn(b[k]);
        float p = P[i * K + k];
        if (shrinkGrad) g *= sgn(p) * sgn(p - SHRINK_C);   // d shrink/dp a.e.
        float mm = BETA1 * m[i * K + k] + (1.f - BETA1) * g;
        float vv = BETA2 * v[i * K + k] + (1.f - BETA2) * g * g;
        m[i * K + k] = mm;
        v[i * K + k] = vv;
        p -= LR * (mm / bias1) / (sqrtf(vv / bias2) + ADAM_EPS);
        P[i * K + k] = p;
        B[i * K + k] = sgn(p) * fmaxf(0.f, fabsf(p - SHRINK_C));   // next B = shrink(P)
    }
}

// out = [shrink(P_final) (8192), A (800000)]. B already holds shrink(P_final).
// Both segments are 16B-aligned and multiples of 4 elements -> float4 copy.
__global__ void output_kernel(const float* __restrict__ B, const float* __restrict__ A,
                              float4* __restrict__ out) {
    int idx = blockIdx.x * blockDim.x + threadIdx.x;   // in float4 units
    const int nB4 = (D * K) / 4;                       // 2048
    const int nTot4 = (D * K + K * T) / 4;             // 202048
    if (idx < nB4) {
        out[idx] = ((const float4*)B)[idx];
    } else if (idx < nTot4) {
        out[idx] = ((const float4*)A)[idx - nB4];
    }
}

extern "C" void kernel_launch(void* const* d_in, const int* in_sizes, int n_in,
                              void* d_out, int out_size, void* d_ws, size_t ws_size,
                              hipStream_t stream) {
    const float* E   = (const float*)d_in[0];   // (D, T)
    const float* Bin = (const float*)d_in[1];   // (D, K)
    const float* A   = (const float*)d_in[2];   // (K, T)

    float* P = (float*)d_ws;
    float* m = P + D * K;
    float* v = m + D * K;
    float* B = v + D * K;
    unsigned long long* slot = (unsigned long long*)(B + D * K);
    float* partial = (float*)(slot + 2);   // N_SLICES * T floats (~1.6 MB)

    init_kernel<<<(D * K + 255) / 256, 256, 0, stream>>>(Bin, P, m, v, B, slot);

    const int cb = (T + 255) / 256;   // 196 column-blocks
    for (int it = 1; it <= 10; ++it) {
        partial_colsum_kernel<<<dim3(cb, N_SLICES), 256, 0, stream>>>(E, A, B, partial);
        reduce_argmax_kernel<<<cb, 256, 0, stream>>>(partial, slot);
        float b1 = 1.f - powf(BETA1, (float)it);
        float b2 = 1.f - powf(BETA2, (float)it);
        update_kernel<<<1, 512, 0, stream>>>(E, A, B, P, m, v, slot, b1, b2,
                                             (it >= 2) ? 1 : 0);
    }

    const int nTot4 = (D * K + K * T) / 4;
    output_kernel<<<(nTot4 + 255) / 256, 256, 0, stream>>>(B, A, (float4*)d_out);
}